// Round 4
// baseline (4200.237 us; speedup 1.0000x reference)
//
#include <hip/hip_runtime.h>
#include <hip/hip_bf16.h>
#include <math.h>

// Problem dims (fixed)
#define T_STEPS 512
#define IN_DIM  1024
#define H_DIM   2048
#define Y_DIM   1024

// K2 geometry: 128 blocks x 512 threads (8 waves), 16 cols/block, 2 cols/wave.
#define NBLK2   128
#define BT2     512
#define NLINE   8                    // barrier lines
#define BLKS_PER_LINE (NBLK2 / NLINE)  // 16 adds per line per step

// ---------- helpers ----------
static __device__ __forceinline__ unsigned short f2bf(float f) {
    unsigned u = __float_as_uint(f);
    unsigned r = (u + 0x7FFFu + ((u >> 16) & 1u)) >> 16;   // RNE
    return (unsigned short)r;
}
static __device__ __forceinline__ float bflo(unsigned p) { return __uint_as_float(p << 16); }
static __device__ __forceinline__ float bfhi(unsigned p) { return __uint_as_float(p & 0xFFFF0000u); }

// ---------- K1 / K3: tiled fp32 GEMM, C[M,N] = A[M,K] @ B[K,N] + bias[N] ----------
// 64x128 tile, TK=16, 256 threads, 4x8 acc: 32 FMA per 3 ds_read_b128.
#define TM 64
#define TN 128
#define TK 16

__global__ __launch_bounds__(256) void gemm_bias(
    const float* __restrict__ A, const float* __restrict__ B,
    const float* __restrict__ bias, float* __restrict__ C,
    int M, int N, int K, int lda, int ldb, int ldc)
{
    __shared__ float As[TK][TM + 4];    // 68-float rows
    __shared__ float Bs[TK][TN + 4];    // 132-float rows (16B-aligned stride)

    const int n0 = blockIdx.x * TN;
    const int m0 = blockIdx.y * TM;
    const int tid = threadIdx.x;
    const int tx = tid & 15;        // N: 8 floats each
    const int ty = tid >> 4;        // M: 4 rows each

    float acc[4][8] = {};

    for (int k0 = 0; k0 < K; k0 += TK) {
        // A tile 64x16, transposed into As[kk][mm]; one float4 per thread
        {
            int mm = tid & 63, kq = tid >> 6;      // kq in 0..3
            float4 a = *(const float4*)&A[(m0 + mm) * lda + k0 + 4 * kq];
            As[4 * kq + 0][mm] = a.x;
            As[4 * kq + 1][mm] = a.y;
            As[4 * kq + 2][mm] = a.z;
            As[4 * kq + 3][mm] = a.w;
        }
        // B tile 16x128; two float4 per thread
        #pragma unroll
        for (int l = tid; l < 512; l += 256) {
            int kk = l >> 5, jj = (l & 31) * 4;
            *(float4*)&Bs[kk][jj] = *(const float4*)&B[(k0 + kk) * ldb + n0 + jj];
        }
        __syncthreads();
        #pragma unroll
        for (int kk = 0; kk < TK; ++kk) {
            float4 a  = *(const float4*)&As[kk][ty * 4];
            float4 b0 = *(const float4*)&Bs[kk][tx * 8];
            float4 b1 = *(const float4*)&Bs[kk][tx * 8 + 4];
            const float av[4] = {a.x, a.y, a.z, a.w};
            const float bv[8] = {b0.x, b0.y, b0.z, b0.w, b1.x, b1.y, b1.z, b1.w};
            #pragma unroll
            for (int r = 0; r < 4; ++r)
                #pragma unroll
                for (int c = 0; c < 8; ++c)
                    acc[r][c] = fmaf(av[r], bv[c], acc[r][c]);
        }
        __syncthreads();
    }

    float4 bv0 = *(const float4*)&bias[n0 + tx * 8];
    float4 bv1 = *(const float4*)&bias[n0 + tx * 8 + 4];
    const float bb[8] = {bv0.x, bv0.y, bv0.z, bv0.w, bv1.x, bv1.y, bv1.z, bv1.w};
    #pragma unroll
    for (int r = 0; r < 4; ++r) {
        float4 o0, o1;
        o0.x = acc[r][0] + bb[0]; o0.y = acc[r][1] + bb[1];
        o0.z = acc[r][2] + bb[2]; o0.w = acc[r][3] + bb[3];
        o1.x = acc[r][4] + bb[4]; o1.y = acc[r][5] + bb[5];
        o1.z = acc[r][6] + bb[6]; o1.w = acc[r][7] + bb[7];
        float* cp = &C[(m0 + ty * 4 + r) * ldc + n0 + tx * 8];
        *(float4*)cp = o0;
        *(float4*)(cp + 4) = o1;
    }
}

// ---------- K2: persistent sequential recurrence ----------
// 128 blocks; wave w owns columns j0 = jb+2w, j0+1. Recurrent weights live in
// REGISTERS (64 VGPR/thread of packed bf16 pairs). All cross-block data moves
// via agent-scope relaxed atomics (bypass L1/L2 -> shared coherence point).
// Barrier: each block adds 1 to its group line; consumers poll all 8 lines
// directly with 8 lanes (no root hop).
__global__ __launch_bounds__(BT2) void gru_seq(
    const float* __restrict__ Wu_h,   // = Wu + IN_DIM*H_DIM
    const float* __restrict__ Wc_h,
    const float* __restrict__ XU,     // [T,H]  x@Wu_x + bu
    const float* __restrict__ XC,     // [T,H]  x@Wc_x + bc
    const float* __restrict__ h0,     // [H]
    float* __restrict__ H,            // [T,H]
    unsigned* __restrict__ bar)       // 8 lines at 256B spacing
{
    const int tid  = threadIdx.x;
    const int w    = tid >> 6;
    const int lane = tid & 63;
    const int jb   = blockIdx.x * 16;
    const int j0   = jb + 2 * w;           // even -> 8B-aligned pairs

    // ---- one-time weight staging into registers ----
    // wr[0]=Wu col j0, wr[1]=Wu col j0+1, wr[2]=Wc col j0, wr[3]=Wc col j0+1
    unsigned wr[4][16];
    {
        const float* Wm[2] = {Wu_h, Wc_h};
        #pragma unroll
        for (int m = 0; m < 2; ++m) {
            #pragma unroll
            for (int c = 0; c < 2; ++c) {
                const float* Wp = Wm[m] + j0 + c;
                #pragma unroll
                for (int i = 0; i < 16; ++i) {
                    int p = i * 64 + lane;
                    float v0 = Wp[(size_t)(2 * p) * H_DIM];
                    float v1 = Wp[(size_t)(2 * p + 1) * H_DIM];
                    wr[2 * m + c][i] = (unsigned)f2bf(v0) | ((unsigned)f2bf(v1) << 16);
                }
            }
        }
    }

    unsigned* mygrp = bar + (blockIdx.x & (NLINE - 1)) * 64;

    for (int t = 0; t < T_STEPS; ++t) {
        // prefetch x-contributions (normal cached loads; issue before the spin)
        float2 xu = make_float2(0.f, 0.f), xc = make_float2(0.f, 0.f);
        if (lane == 0) {
            xu = *(const float2*)(XU + (size_t)t * H_DIM + j0);
            xc = *(const float2*)(XC + (size_t)t * H_DIM + j0);
        }

        // ---- wait for step t-1: poll all 8 lines in parallel (no root) ----
        if (t > 0) {
            if (tid < NLINE) {
                unsigned tgt = (unsigned)t * BLKS_PER_LINE;
                while (__hip_atomic_load(bar + tid * 64, __ATOMIC_RELAXED,
                                         __HIP_MEMORY_SCOPE_AGENT) < tgt) {
                    __builtin_amdgcn_s_sleep(1);
                }
            }
            __syncthreads();
        }

        const float* hsrc = t ? (H + (size_t)(t - 1) * H_DIM) : h0;
        const unsigned long long* h64 = (const unsigned long long*)hsrc;

        float2 hp = make_float2(0.f, 0.f);
        if (lane == 0) {
            unsigned long long u = __hip_atomic_load(
                (const unsigned long long*)(hsrc + j0),
                __ATOMIC_RELAXED, __HIP_MEMORY_SCOPE_AGENT);
            hp.x = __uint_as_float((unsigned)u);
            hp.y = __uint_as_float((unsigned)(u >> 32));
        }

        float a0 = 0.f, a1 = 0.f, a2 = 0.f, a3 = 0.f;  // u@j0, u@j0+1, c@j0, c@j0+1
        #pragma unroll
        for (int i = 0; i < 16; ++i) {
            unsigned long long v = __hip_atomic_load(h64 + i * 64 + lane,
                                       __ATOMIC_RELAXED, __HIP_MEMORY_SCOPE_AGENT);
            float hx = __uint_as_float((unsigned)v);
            float hy = __uint_as_float((unsigned)(v >> 32));
            unsigned pu0 = wr[0][i], pu1 = wr[1][i];
            unsigned pc0 = wr[2][i], pc1 = wr[3][i];
            a0 = fmaf(hx, bflo(pu0), a0); a0 = fmaf(hy, bfhi(pu0), a0);
            a1 = fmaf(hx, bflo(pu1), a1); a1 = fmaf(hy, bfhi(pu1), a1);
            a2 = fmaf(hx, bflo(pc0), a2); a2 = fmaf(hy, bfhi(pc0), a2);
            a3 = fmaf(hx, bflo(pc1), a3); a3 = fmaf(hy, bfhi(pc1), a3);
        }
        #pragma unroll
        for (int off = 32; off; off >>= 1) {
            a0 += __shfl_down(a0, off);
            a1 += __shfl_down(a1, off);
            a2 += __shfl_down(a2, off);
            a3 += __shfl_down(a3, off);
        }
        if (lane == 0) {
            float u0 = 1.f / (1.f + expf(-(a0 + xu.x)));
            float u1 = 1.f / (1.f + expf(-(a1 + xu.y)));
            float c0 = tanhf(a2 + xc.x);
            float c1 = tanhf(a3 + xc.y);
            float hn0 = u0 * c0 + (1.f - u0) * hp.x;
            float hn1 = u1 * c1 + (1.f - u1) * hp.y;
            unsigned long long pv = (unsigned long long)__float_as_uint(hn0) |
                                    ((unsigned long long)__float_as_uint(hn1) << 32);
            __hip_atomic_store((unsigned long long*)(H + (size_t)t * H_DIM + j0), pv,
                               __ATOMIC_RELAXED, __HIP_MEMORY_SCOPE_AGENT);
        }

        // drain sc1 store, block-arrive, signal (1 add per block, no root)
        asm volatile("s_waitcnt vmcnt(0)" ::: "memory");
        __syncthreads();
        if (tid == 0 && t < T_STEPS - 1) {
            __hip_atomic_fetch_add(mygrp, 1u,
                                   __ATOMIC_RELAXED, __HIP_MEMORY_SCOPE_AGENT);
        }
    }
}

extern "C" void kernel_launch(void* const* d_in, const int* in_sizes, int n_in,
                              void* d_out, int out_size, void* d_ws, size_t ws_size,
                              hipStream_t stream)
{
    const float* x   = (const float*)d_in[0];   // [1,512,1024]
    const float* h0  = (const float*)d_in[1];   // [2048]
    const float* Wc  = (const float*)d_in[2];   // [3072,2048]
    const float* Wu  = (const float*)d_in[3];   // [3072,2048]
    const float* bc  = (const float*)d_in[4];   // [2048]
    const float* bu  = (const float*)d_in[5];   // [2048]
    const float* Why = (const float*)d_in[6];   // [2048,1024]
    const float* by  = (const float*)d_in[7];   // [1024]
    float* out = (float*)d_out;                 // ys[512*1024] then h_final[2048]

    float* ws = (float*)d_ws;
    float* XU = ws;                              // 512*2048 floats
    float* XC = ws + (T_STEPS * H_DIM);          // 512*2048
    float* H  = ws + 2 * (T_STEPS * H_DIM);      // 512*2048
    unsigned* bar = (unsigned*)(ws + 3 * (T_STEPS * H_DIM));

    hipMemsetAsync(bar, 0, 4096, stream);

    // K1: XU = x @ Wu[0:1024,:] + bu ; XC = x @ Wc[0:1024,:] + bc
    gemm_bias<<<dim3(H_DIM / TN, T_STEPS / TM), 256, 0, stream>>>(
        x, Wu, bu, XU, T_STEPS, H_DIM, IN_DIM, IN_DIM, H_DIM, H_DIM);
    gemm_bias<<<dim3(H_DIM / TN, T_STEPS / TM), 256, 0, stream>>>(
        x, Wc, bc, XC, T_STEPS, H_DIM, IN_DIM, IN_DIM, H_DIM, H_DIM);

    // K2: sequential recurrence, persistent grid, fence-free sc1 dataflow
    gru_seq<<<NBLK2, BT2, 0, stream>>>(
        Wu + IN_DIM * H_DIM, Wc + IN_DIM * H_DIM, XU, XC, h0, H, bar);

    // K3: ys = H @ Why + by
    gemm_bias<<<dim3(Y_DIM / TN, T_STEPS / TM), 256, 0, stream>>>(
        H, Why, by, out, T_STEPS, Y_DIM, H_DIM, H_DIM, Y_DIM, Y_DIM);

    // h_final = H[511]
    hipMemcpyAsync(out + T_STEPS * Y_DIM, H + (T_STEPS - 1) * H_DIM,
                   H_DIM * sizeof(float), hipMemcpyDeviceToDevice, stream);
}